// Round 16
// baseline (681.981 us; speedup 1.0000x reference)
//
#include <hip/hip_runtime.h>
#include <hip/hip_fp16.h>

// ---------------------------------------------------------------------------
// GAT 2-layer forward. CSR owner-computes, edge-parallel alpha, fused denom.
// Layer1: in=128, H=8, F=32.  Layer2: in=32, H=8, F=16.  N=1e5, E=1.6e6.
// r14 (645us): accounting says the 2x k_alpha2 (serial per-(node,head))
// cost ~200us. This round:
//  - k_scatter also writes epos[e] = CSR position.
//  - k_alpha_e: edge-parallel, 2x32B gathers + 8 exps + 16B store; no loops.
//  - k_agg_ex2: denominator accumulated IN the agg edge loop (den[k]+=ex),
//    s = sum acc[k]/(den[k]+eps); rinv + denominator pass deleted.
// Identical arithmetic/order to r14 (absmax 4.88e-4 expected unchanged).
// (Resubmission: r15 failed on pod disk-full before compile.)
// Softmax without max-subtraction (O(1) logits; validated r6-r8, r14).
// ---------------------------------------------------------------------------

__device__ __forceinline__ float lrelu_exp(float v) {
    v = v > 0.f ? v : 0.2f * v;
    return __expf(v);
}

__global__ __launch_bounds__(256) void k_zero(float* __restrict__ p, int n) {
    int i = blockIdx.x * 256 + threadIdx.x;
    const int stride = gridDim.x * 256;
    for (; i < n; i += stride) p[i] = 0.f;
}

__global__ __launch_bounds__(256) void k_zero_int(int* __restrict__ p, int n) {
    int i = blockIdx.x * 256 + threadIdx.x;
    const int stride = gridDim.x * 256;
    for (; i < n; i += stride) p[i] = 0;
}

// ---------------- CSR build ----------------
__global__ __launch_bounds__(256) void k_hist(const int* __restrict__ ei,
                                              int* __restrict__ deg, int E) {
    const int e = blockIdx.x * 256 + threadIdx.x;
    if (e < E) atomicAdd(&deg[ei[E + e]], 1);
}

__global__ __launch_bounds__(256) void k_scan_block(const int* __restrict__ deg,
                                                    int* __restrict__ rowptr,
                                                    int* __restrict__ bsum, int N) {
    __shared__ int s[256];
    const int t = threadIdx.x;
    const int i = blockIdx.x * 256 + t;
    const int v = (i < N) ? deg[i] : 0;
    s[t] = v;
    __syncthreads();
    for (int off = 1; off < 256; off <<= 1) {
        const int tv = (t >= off) ? s[t - off] : 0;
        __syncthreads();
        s[t] += tv;
        __syncthreads();
    }
    if (i < N) rowptr[i] = s[t] - v;
    if (t == 255) bsum[blockIdx.x] = s[255];
}

__global__ __launch_bounds__(1024) void k_scan_sums(int* __restrict__ bsum, int NB) {
    __shared__ int s[1024];
    const int t = threadIdx.x;
    const int v = (t < NB) ? bsum[t] : 0;
    s[t] = v;
    __syncthreads();
    for (int off = 1; off < 1024; off <<= 1) {
        const int tv = (t >= off) ? s[t - off] : 0;
        __syncthreads();
        s[t] += tv;
        __syncthreads();
    }
    if (t < NB) bsum[t] = s[t] - v;
}

__global__ __launch_bounds__(256) void k_scan_add(int* __restrict__ rowptr,
                                                  const int* __restrict__ bsum,
                                                  int* __restrict__ cursor, int N, int E) {
    const int i = blockIdx.x * 256 + threadIdx.x;
    if (i < N) {
        const int r = rowptr[i] + bsum[blockIdx.x];
        rowptr[i] = r;
        cursor[i] = r;
    }
    if (i == 0) rowptr[N] = E;
}

// Scatter; optionally records epos[e] = CSR slot of edge e (edge order).
__global__ __launch_bounds__(256) void k_scatter(const int* __restrict__ ei,
                                                 int* __restrict__ cursor,
                                                 int* __restrict__ esrc,
                                                 int* __restrict__ epos, int E) {
    const int e = blockIdx.x * 256 + threadIdx.x;
    if (e >= E) return;
    const int src = ei[e];
    const int dst = ei[E + e];
    const int pos = atomicAdd(&cursor[dst], 1);
    esrc[pos] = src;
    if (epos) epos[e] = pos;
}

// ---------------- main-path GEMM: 4x8 register tile, W in LDS ----------------
// x[N,IN] @ W[IN,C] -> h fp16 [N, F, 8] (idx = f*8 + head; head=c/F, f=c%F).
template <int IN, int C, int F>
__global__ __launch_bounds__(256) void k_gemm_big(const float* __restrict__ x,
                                                  const float* __restrict__ W,
                                                  __half* __restrict__ h, int N) {
    constexpr int CJ = C / 32;
    constexpr int KC = 32;
    __shared__ float xs[32 * IN];
    __shared__ float wlds[KC * (C + 4)];
    const int t  = threadIdx.x;
    const int n0 = blockIdx.x * 32;

    const float4* src4 = (const float4*)(x + (size_t)n0 * IN);
    float4* xs4 = (float4*)xs;
    constexpr int NV = 32 * IN / 4;
    for (int idx = t; idx < NV; idx += 256) {
        const int row = idx / (IN / 4);
        xs4[idx] = (n0 + row < N) ? src4[idx] : make_float4(0.f, 0.f, 0.f, 0.f);
    }

    const int tc = t & 31;
    const int tr = t >> 5;
    float acc[4][CJ];
#pragma unroll
    for (int i = 0; i < 4; ++i)
#pragma unroll
        for (int j = 0; j < CJ; ++j) acc[i][j] = 0.f;

#pragma unroll 1
    for (int kc = 0; kc < IN; kc += KC) {
        __syncthreads();
        for (int idx = t; idx < KC * C; idx += 256) {
            const int k = idx / C, c = idx % C;
            wlds[k * (C + 4) + c] = W[(size_t)(kc + k) * C + c];
        }
        __syncthreads();
#pragma unroll 1
        for (int q = 0; q < KC / 4; ++q) {
            float4 xv[4];
#pragma unroll
            for (int i = 0; i < 4; ++i)
                xv[i] = *(const float4*)&xs[(tr * 4 + i) * IN + kc + q * 4];
#pragma unroll
            for (int kk = 0; kk < 4; ++kk) {
                float wv[CJ];
#pragma unroll
                for (int j = 0; j < CJ; ++j)
                    wv[j] = wlds[(q * 4 + kk) * (C + 4) + tc + j * 32];
#pragma unroll
                for (int i = 0; i < 4; ++i) {
                    const float xvv = ((const float*)&xv[i])[kk];
#pragma unroll
                    for (int j = 0; j < CJ; ++j)
                        acc[i][j] = fmaf(xvv, wv[j], acc[i][j]);
                }
            }
        }
    }

    if constexpr (C == 256 && F == 32) {
#pragma unroll
        for (int i = 0; i < 4; ++i) {
            const int r = n0 + tr * 4 + i;
            if (r < N) {
                __half tmp[8];
#pragma unroll
                for (int j = 0; j < 8; ++j) tmp[j] = __float2half(acc[i][j]);
                *(float4*)(h + (size_t)r * 256 + tc * 8) = *(const float4*)tmp;
            }
        }
    } else {
#pragma unroll
        for (int i = 0; i < 4; ++i) {
            const int r = n0 + tr * 4 + i;
            if (r < N) {
#pragma unroll
                for (int j = 0; j < CJ; ++j) {
                    const int c = tc + j * 32;
                    h[(size_t)r * C + (c % F) * 8 + (c / F)] = __float2half(acc[i][j]);
                }
            }
        }
    }
}

// Attention dots from fp16 h [N, F, HG]; writes a_s/a_d [N,8] at head hb+hl.
template <int F, int HG>
__global__ __launch_bounds__(256) void k_dots_h(const __half* __restrict__ h,
                                                const float* __restrict__ atts,
                                                const float* __restrict__ attd,
                                                float* __restrict__ as_,
                                                float* __restrict__ ad_, int N, int hb) {
    const int i = blockIdx.x * 256 + threadIdx.x;
    if (i >= N * HG) return;
    const int n  = i / HG;
    const int hl = i % HG;
    const int hg = hb + hl;
    const __half* hp = h + (size_t)n * (F * HG) + hl;
    const float* sv = atts + hg * F;
    const float* dv = attd + hg * F;
    float s = 0.f, d = 0.f;
#pragma unroll
    for (int f = 0; f < F; ++f) {
        const float v = __half2float(hp[f * HG]);
        s = fmaf(v, sv[f], s);
        d = fmaf(v, dv[f], d);
    }
    as_[(size_t)n * 8 + hg] = s;
    ad_[(size_t)n * 8 + hg] = d;
}

// Edge-parallel alpha: one thread per edge. 2x32B gathers, 8 exps, 16B store
// at the edge's CSR slot. No loops, no degree divergence.
__global__ __launch_bounds__(256) void k_alpha_e(const int* __restrict__ ei,
                                                 const int* __restrict__ epos,
                                                 const float* __restrict__ as_,
                                                 const float* __restrict__ ad_,
                                                 __half* __restrict__ exbuf, int E) {
    const int e = blockIdx.x * 256 + threadIdx.x;
    if (e >= E) return;
    const int src = ei[e];
    const int dst = ei[E + e];
    const int pos = epos[e];
    const float4 s0 = *(const float4*)(as_ + (size_t)src * 8);
    const float4 s1 = *(const float4*)(as_ + (size_t)src * 8 + 4);
    const float4 d0 = *(const float4*)(ad_ + (size_t)dst * 8);
    const float4 d1 = *(const float4*)(ad_ + (size_t)dst * 8 + 4);
    __half tmp[8];
    tmp[0] = __float2half(lrelu_exp(s0.x + d0.x));
    tmp[1] = __float2half(lrelu_exp(s0.y + d0.y));
    tmp[2] = __float2half(lrelu_exp(s0.z + d0.z));
    tmp[3] = __float2half(lrelu_exp(s0.w + d0.w));
    tmp[4] = __float2half(lrelu_exp(s1.x + d1.x));
    tmp[5] = __float2half(lrelu_exp(s1.y + d1.y));
    tmp[6] = __float2half(lrelu_exp(s1.z + d1.z));
    tmp[7] = __float2half(lrelu_exp(s1.w + d1.w));
    *(float4*)(exbuf + (size_t)pos * 8) = *(const float4*)tmp;
}

// Single-pass aggregation; denominator fused into the edge loop.
// thread=(node,f).  s = sum_k acc[k]/(den[k]+eps);
// MODE 1: out = relu(0.125*s + bias)   MODE 2: out = 0.125*s + bias
template <int F, int MODE>
__global__ __launch_bounds__(256) void k_agg_ex2(const int* __restrict__ rowptr,
                                                 const int* __restrict__ esrc,
                                                 const __half* __restrict__ exbuf,
                                                 const __half* __restrict__ h,
                                                 const float* __restrict__ bias,
                                                 float* __restrict__ outp, int N) {
    constexpr int NPB = 256 / F;
    const int n = blockIdx.x * NPB + threadIdx.x / F;
    const int f = threadIdx.x % F;
    if (n >= N) return;
    const int r0 = rowptr[n], r1 = rowptr[n + 1];

    float acc[8], den[8];
#pragma unroll
    for (int k = 0; k < 8; ++k) { acc[k] = 0.f; den[k] = 0.f; }

    for (int e = r0; e < r1; ++e) {
        const int src = esrc[e];
        const float4 exr = *(const float4*)(exbuf + (size_t)e * 8);
        const float4 raw = *(const float4*)(h + (size_t)src * (F * 8) + f * 8);
        const __half2* e2 = (const __half2*)&exr;
        const __half2* h2 = (const __half2*)&raw;
#pragma unroll
        for (int k = 0; k < 4; ++k) {
            const float2 ef = __half22float2(e2[k]);
            const float2 hf = __half22float2(h2[k]);
            acc[2 * k]     = fmaf(ef.x, hf.x, acc[2 * k]);
            acc[2 * k + 1] = fmaf(ef.y, hf.y, acc[2 * k + 1]);
            den[2 * k]     += ef.x;
            den[2 * k + 1] += ef.y;
        }
    }
    float s = 0.f;
#pragma unroll
    for (int k = 0; k < 8; ++k) s += acc[k] / (den[k] + 1e-16f);
    float v = 0.125f * s + bias[f];
    if constexpr (MODE == 1) v = v > 0.f ? v : 0.f;
    outp[(size_t)n * F + f] = v;
}

// ---------------- fallback path (r8-proven, single HG=4 instantiation) -------
template <int IN, int C, int OW, int F>
__global__ __launch_bounds__(256) void k_gemm_h(const float* __restrict__ x,
                                                const float* __restrict__ W,
                                                __half* __restrict__ h, int N, int c0) {
    constexpr int HG = C / F;
    __shared__ float xs[32 * IN];
    const int t  = threadIdx.x;
    const int n0 = blockIdx.x * 32;
    const float4* src4 = (const float4*)(x + (size_t)n0 * IN);
    float4* xs4 = (float4*)xs;
    constexpr int NV = 32 * IN / 4;
    for (int idx = t; idx < NV; idx += 256) {
        const int row = idx / (IN / 4);
        xs4[idx] = (n0 + row < N) ? src4[idx] : make_float4(0.f, 0.f, 0.f, 0.f);
    }
    __syncthreads();
    const int idx = t % C;
    const int r0  = t / C;
    constexpr int RSTEP = 256 / C;
    constexpr int RPT   = 32 / RSTEP;
    const int f  = idx / HG;
    const int hd = idx % HG;
    float acc[RPT];
#pragma unroll
    for (int i = 0; i < RPT; ++i) acc[i] = 0.f;
    const float* Wc = W + c0 + hd * F + f;
#pragma unroll 1
    for (int k = 0; k < IN; k += 4) {
        const float w0 = Wc[(k + 0) * OW];
        const float w1 = Wc[(k + 1) * OW];
        const float w2 = Wc[(k + 2) * OW];
        const float w3 = Wc[(k + 3) * OW];
#pragma unroll
        for (int i = 0; i < RPT; ++i) {
            const int r = r0 + i * RSTEP;
            const float4 xv = *(const float4*)&xs[r * IN + k];
            acc[i] = fmaf(xv.x, w0, fmaf(xv.y, w1, fmaf(xv.z, w2, fmaf(xv.w, w3, acc[i]))));
        }
    }
#pragma unroll
    for (int i = 0; i < RPT; ++i) {
        const int r = r0 + i * RSTEP;
        if (n0 + r < N) h[(size_t)(n0 + r) * C + idx] = __float2half(acc[i]);
    }
}

template <int HG>
__global__ __launch_bounds__(256) void k_denom(const int* __restrict__ rowptr,
                                               const int* __restrict__ esrc,
                                               const float* __restrict__ as_,
                                               const float* __restrict__ ad_,
                                               float* __restrict__ rinv, int N, int hb) {
    const int i = blockIdx.x * 256 + threadIdx.x;
    if (i >= N * HG) return;
    const int n  = i / HG;
    const int hl = i % HG;
    const float ad = ad_[(size_t)n * 8 + hb + hl];
    const int r0 = rowptr[n];
    const int r1 = rowptr[n + 1];
    float s = 0.f;
    for (int e = r0; e < r1; ++e)
        s += lrelu_exp(as_[(size_t)esrc[e] * 8 + hb + hl] + ad);
    rinv[(size_t)n * 8 + hb + hl] = 1.f / (s + 1e-16f);
}

template <int F, int HG>
__global__ __launch_bounds__(256) void k_csr_agg_hg(const int* __restrict__ rowptr,
                                                    const int* __restrict__ esrc,
                                                    const float* __restrict__ as_,
                                                    const float* __restrict__ ad_,
                                                    const float* __restrict__ rinv,
                                                    const __half* __restrict__ h,
                                                    float* __restrict__ outp,
                                                    int N, int hb) {
    constexpr int NPB = 256 / F;
    const int n = blockIdx.x * NPB + threadIdx.x / F;
    const int f = threadIdx.x % F;
    if (n >= N) return;
    const int r0 = rowptr[n];
    const int r1 = rowptr[n + 1];
    float ad[HG], rv[HG];
#pragma unroll
    for (int k = 0; k < HG; ++k) {
        ad[k] = ad_[(size_t)n * 8 + hb + k];
        rv[k] = rinv[(size_t)n * 8 + hb + k];
    }
    float a0 = 0.f;
    for (int e = r0; e < r1; ++e) {
        const int src = esrc[e];
        const float* sp = as_ + (size_t)src * 8 + hb;
        const __half* hp = h + (size_t)src * (F * HG) + f * HG;
#pragma unroll
        for (int k = 0; k < HG; ++k) {
            const float al = lrelu_exp(sp[k] + ad[k]) * rv[k];
            a0 = fmaf(al, __half2float(hp[k]), a0);
        }
    }
    outp[(size_t)n * F + f] += 0.125f * a0;
}

__global__ __launch_bounds__(256) void k_relu_bias(float* __restrict__ a,
                                                   const float* __restrict__ b, int total) {
    const int i = blockIdx.x * 256 + threadIdx.x;
    if (i < total) {
        const float v = a[i] + b[i & 31];
        a[i] = v > 0.f ? v : 0.f;
    }
}

__global__ __launch_bounds__(256) void k_bias_inplace(float* __restrict__ a,
                                                      const float* __restrict__ b, int total) {
    const int i = blockIdx.x * 256 + threadIdx.x;
    if (i < total) a[i] += b[i & 15];
}

// ---------------- drivers ----------------
static void csr_build(const int* ei, int* deg, int* rowptr, int* bsum, int* cursor,
                      int* esrc, int* epos, int N, int E, hipStream_t stream) {
    const int NBn = (N + 255) / 256;
    const int NBe = (E + 255) / 256;
    k_zero_int<<<512, 256, 0, stream>>>(deg, N);
    k_hist<<<NBe, 256, 0, stream>>>(ei, deg, E);
    k_scan_block<<<NBn, 256, 0, stream>>>(deg, rowptr, bsum, N);
    k_scan_sums<<<1, 1024, 0, stream>>>(bsum, NBn);
    k_scan_add<<<NBn, 256, 0, stream>>>(rowptr, bsum, cursor, N, E);
    k_scatter<<<NBe, 256, 0, stream>>>(ei, cursor, esrc, epos, E);
}

static void run_full(const float* x, const int* ei,
                     const float* W1, const float* as1, const float* ad1, const float* b1,
                     const float* W2, const float* as2, const float* ad2, const float* b2,
                     float* out, int N, int E, char* ws, hipStream_t stream) {
    auto align256 = [](size_t b) { return (b + 255) & ~(size_t)255; };
    size_t off = 0;
    auto alloc = [&](size_t bytes) { char* p = ws + off; off += align256(bytes); return p; };

    __half* hbuf  = (__half*)alloc((size_t)N * 256 * 2);
    __half* exbuf = (__half*)alloc((size_t)E * 8 * 2);
    float* a_s    = (float*)alloc((size_t)N * 8 * 4);
    float* a_d    = (float*)alloc((size_t)N * 8 * 4);
    float* acc1   = (float*)alloc((size_t)N * 32 * 4);
    int* rowptr   = (int*)alloc((size_t)(N + 1) * 4);
    int* cursor   = (int*)alloc((size_t)N * 4);
    int* deg      = (int*)alloc((size_t)N * 4);
    int* bsum     = (int*)alloc(1024 * 4);
    int* esrc     = (int*)alloc((size_t)E * 4);
    int* epos     = (int*)alloc((size_t)E * 4);

    csr_build(ei, deg, rowptr, bsum, cursor, esrc, epos, N, E, stream);

    const int NBg = (N + 31) / 32;
    const int nbp = (N * 8 + 255) / 256;
    const int NBe = (E + 255) / 256;
    // layer 1
    k_gemm_big<128, 256, 32><<<NBg, 256, 0, stream>>>(x, W1, hbuf, N);
    k_dots_h<32, 8><<<nbp, 256, 0, stream>>>(hbuf, as1, ad1, a_s, a_d, N, 0);
    k_alpha_e<<<NBe, 256, 0, stream>>>(ei, epos, a_s, a_d, exbuf, E);
    k_agg_ex2<32, 1><<<(N + 7) / 8, 256, 0, stream>>>(rowptr, esrc, exbuf, hbuf, b1, acc1, N);
    // layer 2
    k_gemm_big<32, 128, 16><<<NBg, 256, 0, stream>>>(acc1, W2, hbuf, N);
    k_dots_h<16, 8><<<nbp, 256, 0, stream>>>(hbuf, as2, ad2, a_s, a_d, N, 0);
    k_alpha_e<<<NBe, 256, 0, stream>>>(ei, epos, a_s, a_d, exbuf, E);
    k_agg_ex2<16, 2><<<(N + 15) / 16, 256, 0, stream>>>(rowptr, esrc, exbuf, hbuf, b2, out, N);
}

static void run_fallback4(const float* x, const int* ei,
                          const float* W1, const float* as1, const float* ad1, const float* b1,
                          const float* W2, const float* as2, const float* ad2, const float* b2,
                          float* out, int N, int E, char* ws, hipStream_t stream) {
    constexpr int HG = 4;
    auto align256 = [](size_t b) { return (b + 255) & ~(size_t)255; };
    size_t off = 0;
    auto alloc = [&](size_t bytes) { char* p = ws + off; off += align256(bytes); return p; };

    __half* hbuf = (__half*)alloc((size_t)N * HG * 32 * 2);
    float* a_s   = (float*)alloc((size_t)N * 8 * 4);
    float* a_d   = (float*)alloc((size_t)N * 8 * 4);
    float* rinv  = (float*)alloc((size_t)N * 8 * 4);
    float* acc1  = (float*)alloc((size_t)N * 32 * 4);
    int* rowptr  = (int*)alloc((size_t)(N + 1) * 4);
    int* cursor  = (int*)alloc((size_t)N * 4);
    int* deg     = (int*)alloc((size_t)N * 4);
    int* bsum    = (int*)alloc(1024 * 4);
    int* esrc    = (int*)alloc((size_t)E * 4);

    csr_build(ei, deg, rowptr, bsum, cursor, esrc, nullptr, N, E, stream);

    k_zero<<<512, 256, 0, stream>>>(acc1, N * 32);
    k_zero<<<512, 256, 0, stream>>>(out, N * 16);

    const int NBn = (N + 255) / 256;
    const int nbp = (N * HG + 255) / 256;

    for (int g = 0; g < 2; ++g) {
        k_gemm_h<128, 128, 256, 32><<<NBn * 8, 256, 0, stream>>>(x, W1, hbuf, N, g * 128);
        k_dots_h<32, HG><<<nbp, 256, 0, stream>>>(hbuf, as1, ad1, a_s, a_d, N, g * HG);
        k_denom<HG><<<nbp, 256, 0, stream>>>(rowptr, esrc, a_s, a_d, rinv, N, g * HG);
        k_csr_agg_hg<32, HG><<<(N + 7) / 8, 256, 0, stream>>>(rowptr, esrc, a_s, a_d, rinv,
                                                              hbuf, acc1, N, g * HG);
    }
    k_relu_bias<<<(N * 32 + 255) / 256, 256, 0, stream>>>(acc1, b1, N * 32);

    for (int g = 0; g < 2; ++g) {
        k_gemm_h<32, 64, 128, 16><<<NBn * 8, 256, 0, stream>>>(acc1, W2, hbuf, N, g * 64);
        k_dots_h<16, HG><<<nbp, 256, 0, stream>>>(hbuf, as2, ad2, a_s, a_d, N, g * HG);
        k_denom<HG><<<nbp, 256, 0, stream>>>(rowptr, esrc, a_s, a_d, rinv, N, g * HG);
        k_csr_agg_hg<16, HG><<<(N + 15) / 16, 256, 0, stream>>>(rowptr, esrc, a_s, a_d, rinv,
                                                                hbuf, out, N, g * HG);
    }
    k_bias_inplace<<<(N * 16 + 255) / 256, 256, 0, stream>>>(out, b2, N * 16);
}

extern "C" void kernel_launch(void* const* d_in, const int* in_sizes, int n_in,
                              void* d_out, int out_size, void* d_ws, size_t ws_size,
                              hipStream_t stream) {
    const float* x   = (const float*)d_in[0];
    const int*   ei  = (const int*)d_in[1];
    const float* W1  = (const float*)d_in[2];
    const float* as1 = (const float*)d_in[3];
    const float* ad1 = (const float*)d_in[4];
    const float* b1  = (const float*)d_in[5];
    const float* W2  = (const float*)d_in[6];
    const float* as2 = (const float*)d_in[7];
    const float* ad2 = (const float*)d_in[8];
    const float* b2  = (const float*)d_in[9];
    float* out = (float*)d_out;

    const int N = in_sizes[0] / 128;
    const int E = in_sizes[1] / 2;

    // hbuf + exbuf + a_s + a_d + acc1 + ints(rowptr,cursor,deg,bsum,esrc,epos)
    const size_t need_full = (size_t)2 * N * 256 + (size_t)2 * E * 8 +
                             (size_t)4 * N * (8 + 8 + 32) +
                             (size_t)4 * (3 * N + 1 + 1024 + 2 * (size_t)E) + 16 * 256;
    char* ws = (char*)d_ws;
    if (ws_size >= need_full) {
        run_full(x, ei, W1, as1, ad1, b1, W2, as2, ad2, b2, out, N, E, ws, stream);
    } else {
        run_fallback4(x, ei, W1, as1, ad1, b1, W2, as2, ad2, b2, out, N, E, ws, stream);
    }
}

// Round 17
// 577.416 us; speedup vs baseline: 1.1811x; 1.1811x over previous
//
#include <hip/hip_runtime.h>
#include <hip/hip_fp16.h>

// ---------------------------------------------------------------------------
// GAT 2-layer forward. Bucket-sorted CSR (no global atomics), edge-parallel
// alpha with coalesced writes, fused-denominator aggregation.
// Layer1: in=128, H=8, F=32.  Layer2: in=32, H=8, F=16.  N=1e5, E=1.6e6.
// r16 profile: k_scatter 136us (111MB of 32B-amplified atomic+scattered
// writes, VALU 0.3%) + k_hist ~50us = CSR build ~190us at the random-write
// ceiling. Fix: two-level bucket sort (dst>>9, 196 buckets): per-block LDS
// histograms -> flat scan -> bucketed 8B records -> per-bucket LDS CSR.
// All scatter confined to L2-resident bucket windows; zero global atomics.
// sdst[] enables slot-parallel alpha with coalesced exbuf stores.
// Softmax without max-subtraction (O(1) logits; validated r6-r16).
// ---------------------------------------------------------------------------

__device__ __forceinline__ float lrelu_exp(float v) {
    v = v > 0.f ? v : 0.2f * v;
    return __expf(v);
}

__global__ __launch_bounds__(256) void k_zero(float* __restrict__ p, int n) {
    int i = blockIdx.x * 256 + threadIdx.x;
    const int stride = gridDim.x * 256;
    for (; i < n; i += stride) p[i] = 0.f;
}

__global__ __launch_bounds__(256) void k_zero_int(int* __restrict__ p, int n) {
    int i = blockIdx.x * 256 + threadIdx.x;
    const int stride = gridDim.x * 256;
    for (; i < n; i += stride) p[i] = 0;
}

// ---------------- bucket-sort CSR build (main path) ----------------
// Bucket = dst >> 9 (512 nodes/bucket), nbkt <= 256 for N <= 131072.
// Chunk = 4096 edges/block.

__global__ __launch_bounds__(256) void k_bhist(const int* __restrict__ ei,
                                               int* __restrict__ gcnt,
                                               int E, int nblk, int nbkt) {
    __shared__ int cnt[256];
    const int t = threadIdx.x;
    cnt[t] = 0;
    __syncthreads();
    const int base = blockIdx.x * 4096;
#pragma unroll
    for (int i = 0; i < 16; ++i) {
        const int e = base + i * 256 + t;
        if (e < E) atomicAdd(&cnt[ei[E + e] >> 9], 1);
    }
    __syncthreads();
    if (t < nbkt) gcnt[t * nblk + blockIdx.x] = cnt[t];
}

// Exclusive scan of flat count matrix (L = nbkt*nblk, bucket-major).
__global__ __launch_bounds__(1024) void k_scan_flat(int* __restrict__ g, int L) {
    __shared__ int s[1024];
    const int t = threadIdx.x;
    const int strip = (L + 1023) >> 10;
    const int s0 = t * strip;
    const int s1 = min(s0 + strip, L);
    int sum = 0;
    for (int i = s0; i < s1; ++i) sum += g[i];
    s[t] = sum;
    __syncthreads();
    for (int off = 1; off < 1024; off <<= 1) {
        const int v = (t >= off) ? s[t - off] : 0;
        __syncthreads();
        s[t] += v;
        __syncthreads();
    }
    int run = s[t] - sum;  // exclusive prefix for this strip
    for (int i = s0; i < s1; ++i) { const int v = g[i]; g[i] = run; run += v; }
}

// Scatter (src,dst) records into per-(bucket,block) contiguous runs.
__global__ __launch_bounds__(256) void k_bucket_scatter(const int* __restrict__ ei,
                                                        const int* __restrict__ gbase,
                                                        int2* __restrict__ buf2,
                                                        int E, int nblk) {
    __shared__ int cnt[256];
    const int t = threadIdx.x;
    cnt[t] = 0;
    __syncthreads();
    const int base = blockIdx.x * 4096;
#pragma unroll
    for (int i = 0; i < 16; ++i) {
        const int e = base + i * 256 + t;
        if (e < E) {
            const int src = ei[e];
            const int dst = ei[E + e];
            const int b = dst >> 9;
            const int r = atomicAdd(&cnt[b], 1);
            buf2[gbase[b * nblk + blockIdx.x] + r] = make_int2(src, dst);
        }
    }
}

// Per-bucket fine CSR: LDS hist(512) -> scan -> rowptr + esrc/sdst (dense).
__global__ __launch_bounds__(256) void k_bucket_csr(const int2* __restrict__ buf2,
                                                    const int* __restrict__ gbase,
                                                    int* __restrict__ rowptr,
                                                    int* __restrict__ esrc,
                                                    int* __restrict__ sdst,
                                                    int N, int E, int nblk, int nbkt) {
    __shared__ int hist[512], curs[512], ps[256];
    __shared__ int sh_base, sh_end;
    const int t = threadIdx.x;
    const int b = blockIdx.x;
    const int node0 = b << 9;
    if (t == 0) {
        sh_base = gbase[b * nblk];
        sh_end  = (b + 1 < nbkt) ? gbase[(b + 1) * nblk] : E;
        if (b == 0) rowptr[N] = E;
    }
    hist[t] = 0;
    hist[t + 256] = 0;
    __syncthreads();
    const int eb = sh_base, ee = sh_end;
    for (int e = eb + t; e < ee; e += 256)
        atomicAdd(&hist[buf2[e].y - node0], 1);
    __syncthreads();
    const int p0 = hist[2 * t], p1 = hist[2 * t + 1];
    const int pr = p0 + p1;
    ps[t] = pr;
    __syncthreads();
    for (int off = 1; off < 256; off <<= 1) {
        const int v = (t >= off) ? ps[t - off] : 0;
        __syncthreads();
        ps[t] += v;
        __syncthreads();
    }
    const int e0 = ps[t] - pr;  // exclusive, bucket-local, for node 2t
    curs[2 * t]     = e0;
    curs[2 * t + 1] = e0 + p0;
    const int nn = min(512, N - node0);
    if (2 * t < nn)     rowptr[node0 + 2 * t]     = eb + e0;
    if (2 * t + 1 < nn) rowptr[node0 + 2 * t + 1] = eb + e0 + p0;
    __syncthreads();
    for (int e = eb + t; e < ee; e += 256) {
        const int2 r = buf2[e];
        const int rk = atomicAdd(&curs[r.y - node0], 1);
        esrc[eb + rk] = r.x;
        sdst[eb + rk] = r.y;
    }
}

// ---------------- legacy CSR build (fallback path only) ----------------
__global__ __launch_bounds__(256) void k_hist(const int* __restrict__ ei,
                                              int* __restrict__ deg, int E) {
    const int e = blockIdx.x * 256 + threadIdx.x;
    if (e < E) atomicAdd(&deg[ei[E + e]], 1);
}

__global__ __launch_bounds__(256) void k_scan_block(const int* __restrict__ deg,
                                                    int* __restrict__ rowptr,
                                                    int* __restrict__ bsum, int N) {
    __shared__ int s[256];
    const int t = threadIdx.x;
    const int i = blockIdx.x * 256 + t;
    const int v = (i < N) ? deg[i] : 0;
    s[t] = v;
    __syncthreads();
    for (int off = 1; off < 256; off <<= 1) {
        const int tv = (t >= off) ? s[t - off] : 0;
        __syncthreads();
        s[t] += tv;
        __syncthreads();
    }
    if (i < N) rowptr[i] = s[t] - v;
    if (t == 255) bsum[blockIdx.x] = s[255];
}

__global__ __launch_bounds__(1024) void k_scan_sums(int* __restrict__ bsum, int NB) {
    __shared__ int s[1024];
    const int t = threadIdx.x;
    const int v = (t < NB) ? bsum[t] : 0;
    s[t] = v;
    __syncthreads();
    for (int off = 1; off < 1024; off <<= 1) {
        const int tv = (t >= off) ? s[t - off] : 0;
        __syncthreads();
        s[t] += tv;
        __syncthreads();
    }
    if (t < NB) bsum[t] = s[t] - v;
}

__global__ __launch_bounds__(256) void k_scan_add(int* __restrict__ rowptr,
                                                  const int* __restrict__ bsum,
                                                  int* __restrict__ cursor, int N, int E) {
    const int i = blockIdx.x * 256 + threadIdx.x;
    if (i < N) {
        const int r = rowptr[i] + bsum[blockIdx.x];
        rowptr[i] = r;
        cursor[i] = r;
    }
    if (i == 0) rowptr[N] = E;
}

__global__ __launch_bounds__(256) void k_scatter(const int* __restrict__ ei,
                                                 int* __restrict__ cursor,
                                                 int* __restrict__ esrc, int E) {
    const int e = blockIdx.x * 256 + threadIdx.x;
    if (e >= E) return;
    const int src = ei[e];
    const int dst = ei[E + e];
    const int pos = atomicAdd(&cursor[dst], 1);
    esrc[pos] = src;
}

// ---------------- main-path GEMM: 4x8 register tile, W in LDS ----------------
template <int IN, int C, int F>
__global__ __launch_bounds__(256) void k_gemm_big(const float* __restrict__ x,
                                                  const float* __restrict__ W,
                                                  __half* __restrict__ h, int N) {
    constexpr int CJ = C / 32;
    constexpr int KC = 32;
    __shared__ float xs[32 * IN];
    __shared__ float wlds[KC * (C + 4)];
    const int t  = threadIdx.x;
    const int n0 = blockIdx.x * 32;

    const float4* src4 = (const float4*)(x + (size_t)n0 * IN);
    float4* xs4 = (float4*)xs;
    constexpr int NV = 32 * IN / 4;
    for (int idx = t; idx < NV; idx += 256) {
        const int row = idx / (IN / 4);
        xs4[idx] = (n0 + row < N) ? src4[idx] : make_float4(0.f, 0.f, 0.f, 0.f);
    }

    const int tc = t & 31;
    const int tr = t >> 5;
    float acc[4][CJ];
#pragma unroll
    for (int i = 0; i < 4; ++i)
#pragma unroll
        for (int j = 0; j < CJ; ++j) acc[i][j] = 0.f;

#pragma unroll 1
    for (int kc = 0; kc < IN; kc += KC) {
        __syncthreads();
        for (int idx = t; idx < KC * C; idx += 256) {
            const int k = idx / C, c = idx % C;
            wlds[k * (C + 4) + c] = W[(size_t)(kc + k) * C + c];
        }
        __syncthreads();
#pragma unroll 1
        for (int q = 0; q < KC / 4; ++q) {
            float4 xv[4];
#pragma unroll
            for (int i = 0; i < 4; ++i)
                xv[i] = *(const float4*)&xs[(tr * 4 + i) * IN + kc + q * 4];
#pragma unroll
            for (int kk = 0; kk < 4; ++kk) {
                float wv[CJ];
#pragma unroll
                for (int j = 0; j < CJ; ++j)
                    wv[j] = wlds[(q * 4 + kk) * (C + 4) + tc + j * 32];
#pragma unroll
                for (int i = 0; i < 4; ++i) {
                    const float xvv = ((const float*)&xv[i])[kk];
#pragma unroll
                    for (int j = 0; j < CJ; ++j)
                        acc[i][j] = fmaf(xvv, wv[j], acc[i][j]);
                }
            }
        }
    }

    if constexpr (C == 256 && F == 32) {
#pragma unroll
        for (int i = 0; i < 4; ++i) {
            const int r = n0 + tr * 4 + i;
            if (r < N) {
                __half tmp[8];
#pragma unroll
                for (int j = 0; j < 8; ++j) tmp[j] = __float2half(acc[i][j]);
                *(float4*)(h + (size_t)r * 256 + tc * 8) = *(const float4*)tmp;
            }
        }
    } else {
#pragma unroll
        for (int i = 0; i < 4; ++i) {
            const int r = n0 + tr * 4 + i;
            if (r < N) {
#pragma unroll
                for (int j = 0; j < CJ; ++j) {
                    const int c = tc + j * 32;
                    h[(size_t)r * C + (c % F) * 8 + (c / F)] = __float2half(acc[i][j]);
                }
            }
        }
    }
}

// Attention dots from fp16 h [N, F, HG]; writes a_s/a_d [N,8] at head hb+hl.
template <int F, int HG>
__global__ __launch_bounds__(256) void k_dots_h(const __half* __restrict__ h,
                                                const float* __restrict__ atts,
                                                const float* __restrict__ attd,
                                                float* __restrict__ as_,
                                                float* __restrict__ ad_, int N, int hb) {
    const int i = blockIdx.x * 256 + threadIdx.x;
    if (i >= N * HG) return;
    const int n  = i / HG;
    const int hl = i % HG;
    const int hg = hb + hl;
    const __half* hp = h + (size_t)n * (F * HG) + hl;
    const float* sv = atts + hg * F;
    const float* dv = attd + hg * F;
    float s = 0.f, d = 0.f;
#pragma unroll
    for (int f = 0; f < F; ++f) {
        const float v = __half2float(hp[f * HG]);
        s = fmaf(v, sv[f], s);
        d = fmaf(v, dv[f], d);
    }
    as_[(size_t)n * 8 + hg] = s;
    ad_[(size_t)n * 8 + hg] = d;
}

// Slot-parallel alpha: p = CSR slot. Coalesced esrc/sdst reads, L2 gathers
// of a_s/a_d, COALESCED 16B exbuf store. No loops, no scattered writes.
__global__ __launch_bounds__(256) void k_alpha_csr(const int* __restrict__ esrc,
                                                   const int* __restrict__ sdst,
                                                   const float* __restrict__ as_,
                                                   const float* __restrict__ ad_,
                                                   __half* __restrict__ exbuf, int E) {
    const int p = blockIdx.x * 256 + threadIdx.x;
    if (p >= E) return;
    const int src = esrc[p];
    const int dst = sdst[p];
    const float4 s0 = *(const float4*)(as_ + (size_t)src * 8);
    const float4 s1 = *(const float4*)(as_ + (size_t)src * 8 + 4);
    const float4 d0 = *(const float4*)(ad_ + (size_t)dst * 8);
    const float4 d1 = *(const float4*)(ad_ + (size_t)dst * 8 + 4);
    __half tmp[8];
    tmp[0] = __float2half(lrelu_exp(s0.x + d0.x));
    tmp[1] = __float2half(lrelu_exp(s0.y + d0.y));
    tmp[2] = __float2half(lrelu_exp(s0.z + d0.z));
    tmp[3] = __float2half(lrelu_exp(s0.w + d0.w));
    tmp[4] = __float2half(lrelu_exp(s1.x + d1.x));
    tmp[5] = __float2half(lrelu_exp(s1.y + d1.y));
    tmp[6] = __float2half(lrelu_exp(s1.z + d1.z));
    tmp[7] = __float2half(lrelu_exp(s1.w + d1.w));
    *(float4*)(exbuf + (size_t)p * 8) = *(const float4*)tmp;
}

// Single-pass aggregation; denominator fused into the edge loop.
template <int F, int MODE>
__global__ __launch_bounds__(256) void k_agg_ex2(const int* __restrict__ rowptr,
                                                 const int* __restrict__ esrc,
                                                 const __half* __restrict__ exbuf,
                                                 const __half* __restrict__ h,
                                                 const float* __restrict__ bias,
                                                 float* __restrict__ outp, int N) {
    constexpr int NPB = 256 / F;
    const int n = blockIdx.x * NPB + threadIdx.x / F;
    const int f = threadIdx.x % F;
    if (n >= N) return;
    const int r0 = rowptr[n], r1 = rowptr[n + 1];

    float acc[8], den[8];
#pragma unroll
    for (int k = 0; k < 8; ++k) { acc[k] = 0.f; den[k] = 0.f; }

    for (int e = r0; e < r1; ++e) {
        const int src = esrc[e];
        const float4 exr = *(const float4*)(exbuf + (size_t)e * 8);
        const float4 raw = *(const float4*)(h + (size_t)src * (F * 8) + f * 8);
        const __half2* e2 = (const __half2*)&exr;
        const __half2* h2 = (const __half2*)&raw;
#pragma unroll
        for (int k = 0; k < 4; ++k) {
            const float2 ef = __half22float2(e2[k]);
            const float2 hf = __half22float2(h2[k]);
            acc[2 * k]     = fmaf(ef.x, hf.x, acc[2 * k]);
            acc[2 * k + 1] = fmaf(ef.y, hf.y, acc[2 * k + 1]);
            den[2 * k]     += ef.x;
            den[2 * k + 1] += ef.y;
        }
    }
    float s = 0.f;
#pragma unroll
    for (int k = 0; k < 8; ++k) s += acc[k] / (den[k] + 1e-16f);
    float v = 0.125f * s + bias[f];
    if constexpr (MODE == 1) v = v > 0.f ? v : 0.f;
    outp[(size_t)n * F + f] = v;
}

// ---------------- fallback path (r8-proven) ----------------
template <int IN, int C, int OW, int F>
__global__ __launch_bounds__(256) void k_gemm_h(const float* __restrict__ x,
                                                const float* __restrict__ W,
                                                __half* __restrict__ h, int N, int c0) {
    constexpr int HG = C / F;
    __shared__ float xs[32 * IN];
    const int t  = threadIdx.x;
    const int n0 = blockIdx.x * 32;
    const float4* src4 = (const float4*)(x + (size_t)n0 * IN);
    float4* xs4 = (float4*)xs;
    constexpr int NV = 32 * IN / 4;
    for (int idx = t; idx < NV; idx += 256) {
        const int row = idx / (IN / 4);
        xs4[idx] = (n0 + row < N) ? src4[idx] : make_float4(0.f, 0.f, 0.f, 0.f);
    }
    __syncthreads();
    const int idx = t % C;
    const int r0  = t / C;
    constexpr int RSTEP = 256 / C;
    constexpr int RPT   = 32 / RSTEP;
    const int f  = idx / HG;
    const int hd = idx % HG;
    float acc[RPT];
#pragma unroll
    for (int i = 0; i < RPT; ++i) acc[i] = 0.f;
    const float* Wc = W + c0 + hd * F + f;
#pragma unroll 1
    for (int k = 0; k < IN; k += 4) {
        const float w0 = Wc[(k + 0) * OW];
        const float w1 = Wc[(k + 1) * OW];
        const float w2 = Wc[(k + 2) * OW];
        const float w3 = Wc[(k + 3) * OW];
#pragma unroll
        for (int i = 0; i < RPT; ++i) {
            const int r = r0 + i * RSTEP;
            const float4 xv = *(const float4*)&xs[r * IN + k];
            acc[i] = fmaf(xv.x, w0, fmaf(xv.y, w1, fmaf(xv.z, w2, fmaf(xv.w, w3, acc[i]))));
        }
    }
#pragma unroll
    for (int i = 0; i < RPT; ++i) {
        const int r = r0 + i * RSTEP;
        if (n0 + r < N) h[(size_t)(n0 + r) * C + idx] = __float2half(acc[i]);
    }
}

template <int HG>
__global__ __launch_bounds__(256) void k_denom(const int* __restrict__ rowptr,
                                               const int* __restrict__ esrc,
                                               const float* __restrict__ as_,
                                               const float* __restrict__ ad_,
                                               float* __restrict__ rinv, int N, int hb) {
    const int i = blockIdx.x * 256 + threadIdx.x;
    if (i >= N * HG) return;
    const int n  = i / HG;
    const int hl = i % HG;
    const float ad = ad_[(size_t)n * 8 + hb + hl];
    const int r0 = rowptr[n];
    const int r1 = rowptr[n + 1];
    float s = 0.f;
    for (int e = r0; e < r1; ++e)
        s += lrelu_exp(as_[(size_t)esrc[e] * 8 + hb + hl] + ad);
    rinv[(size_t)n * 8 + hb + hl] = 1.f / (s + 1e-16f);
}

template <int F, int HG>
__global__ __launch_bounds__(256) void k_csr_agg_hg(const int* __restrict__ rowptr,
                                                    const int* __restrict__ esrc,
                                                    const float* __restrict__ as_,
                                                    const float* __restrict__ ad_,
                                                    const float* __restrict__ rinv,
                                                    const __half* __restrict__ h,
                                                    float* __restrict__ outp,
                                                    int N, int hb) {
    constexpr int NPB = 256 / F;
    const int n = blockIdx.x * NPB + threadIdx.x / F;
    const int f = threadIdx.x % F;
    if (n >= N) return;
    const int r0 = rowptr[n];
    const int r1 = rowptr[n + 1];
    float ad[HG], rv[HG];
#pragma unroll
    for (int k = 0; k < HG; ++k) {
        ad[k] = ad_[(size_t)n * 8 + hb + k];
        rv[k] = rinv[(size_t)n * 8 + hb + k];
    }
    float a0 = 0.f;
    for (int e = r0; e < r1; ++e) {
        const int src = esrc[e];
        const float* sp = as_ + (size_t)src * 8 + hb;
        const __half* hp = h + (size_t)src * (F * HG) + f * HG;
#pragma unroll
        for (int k = 0; k < HG; ++k) {
            const float al = lrelu_exp(sp[k] + ad[k]) * rv[k];
            a0 = fmaf(al, __half2float(hp[k]), a0);
        }
    }
    outp[(size_t)n * F + f] += 0.125f * a0;
}

__global__ __launch_bounds__(256) void k_relu_bias(float* __restrict__ a,
                                                   const float* __restrict__ b, int total) {
    const int i = blockIdx.x * 256 + threadIdx.x;
    if (i < total) {
        const float v = a[i] + b[i & 31];
        a[i] = v > 0.f ? v : 0.f;
    }
}

__global__ __launch_bounds__(256) void k_bias_inplace(float* __restrict__ a,
                                                      const float* __restrict__ b, int total) {
    const int i = blockIdx.x * 256 + threadIdx.x;
    if (i < total) a[i] += b[i & 15];
}

// ---------------- drivers ----------------
static void run_full(const float* x, const int* ei,
                     const float* W1, const float* as1, const float* ad1, const float* b1,
                     const float* W2, const float* as2, const float* ad2, const float* b2,
                     float* out, int N, int E, char* ws, hipStream_t stream) {
    auto align256 = [](size_t b) { return (b + 255) & ~(size_t)255; };
    size_t off = 0;
    auto alloc = [&](size_t bytes) { char* p = ws + off; off += align256(bytes); return p; };

    const int NBLKC = (E + 4095) / 4096;
    const int nbkt  = (N + 511) >> 9;
    const int L     = nbkt * NBLKC;

    __half* hbuf  = (__half*)alloc((size_t)N * 256 * 2);
    __half* exbuf = (__half*)alloc((size_t)E * 8 * 2);
    float* a_s    = (float*)alloc((size_t)N * 8 * 4);
    float* a_d    = (float*)alloc((size_t)N * 8 * 4);
    size_t acc_bytes = (size_t)N * 32 * 4;
    size_t buf2_bytes = (size_t)E * 8;
    float* acc1   = (float*)alloc(acc_bytes > buf2_bytes ? acc_bytes : buf2_bytes);
    int2* buf2    = (int2*)acc1;            // aliased: buf2 dead before agg1 writes acc1
    int* rowptr   = (int*)alloc((size_t)(N + 1) * 4);
    int* esrc     = (int*)alloc((size_t)E * 4);
    int* sdst     = (int*)alloc((size_t)E * 4);
    int* gcnt     = (int*)alloc((size_t)L * 4);

    // ---- bucket-sort CSR build (no global atomics) ----
    k_bhist<<<NBLKC, 256, 0, stream>>>(ei, gcnt, E, NBLKC, nbkt);
    k_scan_flat<<<1, 1024, 0, stream>>>(gcnt, L);
    k_bucket_scatter<<<NBLKC, 256, 0, stream>>>(ei, gcnt, buf2, E, NBLKC);
    k_bucket_csr<<<nbkt, 256, 0, stream>>>(buf2, gcnt, rowptr, esrc, sdst, N, E, NBLKC, nbkt);

    const int NBg = (N + 31) / 32;
    const int nbp = (N * 8 + 255) / 256;
    const int NBe = (E + 255) / 256;
    // layer 1
    k_gemm_big<128, 256, 32><<<NBg, 256, 0, stream>>>(x, W1, hbuf, N);
    k_dots_h<32, 8><<<nbp, 256, 0, stream>>>(hbuf, as1, ad1, a_s, a_d, N, 0);
    k_alpha_csr<<<NBe, 256, 0, stream>>>(esrc, sdst, a_s, a_d, exbuf, E);
    k_agg_ex2<32, 1><<<(N + 7) / 8, 256, 0, stream>>>(rowptr, esrc, exbuf, hbuf, b1, acc1, N);
    // layer 2
    k_gemm_big<32, 128, 16><<<NBg, 256, 0, stream>>>(acc1, W2, hbuf, N);
    k_dots_h<16, 8><<<nbp, 256, 0, stream>>>(hbuf, as2, ad2, a_s, a_d, N, 0);
    k_alpha_csr<<<NBe, 256, 0, stream>>>(esrc, sdst, a_s, a_d, exbuf, E);
    k_agg_ex2<16, 2><<<(N + 15) / 16, 256, 0, stream>>>(rowptr, esrc, exbuf, hbuf, b2, out, N);
}

static void run_fallback4(const float* x, const int* ei,
                          const float* W1, const float* as1, const float* ad1, const float* b1,
                          const float* W2, const float* as2, const float* ad2, const float* b2,
                          float* out, int N, int E, char* ws, hipStream_t stream) {
    constexpr int HG = 4;
    auto align256 = [](size_t b) { return (b + 255) & ~(size_t)255; };
    size_t off = 0;
    auto alloc = [&](size_t bytes) { char* p = ws + off; off += align256(bytes); return p; };

    __half* hbuf = (__half*)alloc((size_t)N * HG * 32 * 2);
    float* a_s   = (float*)alloc((size_t)N * 8 * 4);
    float* a_d   = (float*)alloc((size_t)N * 8 * 4);
    float* rinv  = (float*)alloc((size_t)N * 8 * 4);
    float* acc1  = (float*)alloc((size_t)N * 32 * 4);
    int* rowptr  = (int*)alloc((size_t)(N + 1) * 4);
    int* cursor  = (int*)alloc((size_t)N * 4);
    int* deg     = (int*)alloc((size_t)N * 4);
    int* bsum    = (int*)alloc(1024 * 4);
    int* esrc    = (int*)alloc((size_t)E * 4);

    const int NBn = (N + 255) / 256;
    const int NBe = (E + 255) / 256;
    k_zero_int<<<512, 256, 0, stream>>>(deg, N);
    k_hist<<<NBe, 256, 0, stream>>>(ei, deg, E);
    k_scan_block<<<NBn, 256, 0, stream>>>(deg, rowptr, bsum, N);
    k_scan_sums<<<1, 1024, 0, stream>>>(bsum, NBn);
    k_scan_add<<<NBn, 256, 0, stream>>>(rowptr, bsum, cursor, N, E);
    k_scatter<<<NBe, 256, 0, stream>>>(ei, cursor, esrc, E);

    k_zero<<<512, 256, 0, stream>>>(acc1, N * 32);
    k_zero<<<512, 256, 0, stream>>>(out, N * 16);

    const int nbp = (N * HG + 255) / 256;
    for (int g = 0; g < 2; ++g) {
        k_gemm_h<128, 128, 256, 32><<<NBn * 8, 256, 0, stream>>>(x, W1, hbuf, N, g * 128);
        k_dots_h<32, HG><<<nbp, 256, 0, stream>>>(hbuf, as1, ad1, a_s, a_d, N, g * HG);
        k_denom<HG><<<nbp, 256, 0, stream>>>(rowptr, esrc, a_s, a_d, rinv, N, g * HG);
        k_csr_agg_hg<32, HG><<<(N + 7) / 8, 256, 0, stream>>>(rowptr, esrc, a_s, a_d, rinv,
                                                              hbuf, acc1, N, g * HG);
    }
    k_relu_bias<<<(N * 32 + 255) / 256, 256, 0, stream>>>(acc1, b1, N * 32);

    for (int g = 0; g < 2; ++g) {
        k_gemm_h<32, 64, 128, 16><<<NBn * 8, 256, 0, stream>>>(acc1, W2, hbuf, N, g * 64);
        k_dots_h<16, HG><<<nbp, 256, 0, stream>>>(hbuf, as2, ad2, a_s, a_d, N, g * HG);
        k_denom<HG><<<nbp, 256, 0, stream>>>(rowptr, esrc, a_s, a_d, rinv, N, g * HG);
        k_csr_agg_hg<16, HG><<<(N + 15) / 16, 256, 0, stream>>>(rowptr, esrc, a_s, a_d, rinv,
                                                                hbuf, out, N, g * HG);
    }
    k_bias_inplace<<<(N * 16 + 255) / 256, 256, 0, stream>>>(out, b2, N * 16);
}

extern "C" void kernel_launch(void* const* d_in, const int* in_sizes, int n_in,
                              void* d_out, int out_size, void* d_ws, size_t ws_size,
                              hipStream_t stream) {
    const float* x   = (const float*)d_in[0];
    const int*   ei  = (const int*)d_in[1];
    const float* W1  = (const float*)d_in[2];
    const float* as1 = (const float*)d_in[3];
    const float* ad1 = (const float*)d_in[4];
    const float* b1  = (const float*)d_in[5];
    const float* W2  = (const float*)d_in[6];
    const float* as2 = (const float*)d_in[7];
    const float* ad2 = (const float*)d_in[8];
    const float* b2  = (const float*)d_in[9];
    float* out = (float*)d_out;

    const int N = in_sizes[0] / 128;
    const int E = in_sizes[1] / 2;

    const int NBLKC = (E + 4095) / 4096;
    const int nbkt  = (N + 511) >> 9;
    const size_t acc_or_buf2 = ((size_t)N * 32 * 4 > (size_t)E * 8) ? (size_t)N * 32 * 4
                                                                    : (size_t)E * 8;
    const size_t need_full = (size_t)2 * N * 256 + (size_t)2 * E * 8 +
                             (size_t)4 * N * 16 + acc_or_buf2 +
                             (size_t)4 * (N + 1) + (size_t)8 * E +
                             (size_t)4 * nbkt * NBLKC + 16 * 256;
    char* ws = (char*)d_ws;
    if (ws_size >= need_full && nbkt <= 256) {
        run_full(x, ei, W1, as1, ad1, b1, W2, as2, ad2, b2, out, N, E, ws, stream);
    } else {
        run_fallback4(x, ei, W1, as1, ad1, b1, W2, as2, ad2, b2, out, N, E, ws, stream);
    }
}

// Round 18
// 457.756 us; speedup vs baseline: 1.4898x; 1.2614x over previous
//
#include <hip/hip_runtime.h>
#include <hip/hip_fp16.h>

// ---------------------------------------------------------------------------
// GAT 2-layer forward. Bucket-sorted CSR (no global atomics), slot-parallel
// alpha, fused-denominator aggregation.
// Layer1: in=128, H=8, F=32.  Layer2: in=32, H=8, F=16.  N=1e5, E=1.6e6.
// r17 profile (577us): k_scan_flat 127us (single-block scan of 76K entries,
// VALU 0.01% — serial latency chain) and k_gemm_big 129us (Occupancy 29%,
// LDS 49.7KB -> 3 blocks/CU). This round:
//  - hierarchical 3-kernel scan of gcnt (300 blocks -> 300-sum scan -> add).
//  - k_gemm_big KC 32->16: LDS 33KB -> 4 blocks/CU, 16 waves.
//  - k_bucket_scatter caches gbase row in LDS.
// Softmax without max-subtraction (O(1) logits; validated r6-r17).
// ---------------------------------------------------------------------------

__device__ __forceinline__ float lrelu_exp(float v) {
    v = v > 0.f ? v : 0.2f * v;
    return __expf(v);
}

__global__ __launch_bounds__(256) void k_zero(float* __restrict__ p, int n) {
    int i = blockIdx.x * 256 + threadIdx.x;
    const int stride = gridDim.x * 256;
    for (; i < n; i += stride) p[i] = 0.f;
}

__global__ __launch_bounds__(256) void k_zero_int(int* __restrict__ p, int n) {
    int i = blockIdx.x * 256 + threadIdx.x;
    const int stride = gridDim.x * 256;
    for (; i < n; i += stride) p[i] = 0;
}

// ---------------- bucket-sort CSR build (main path) ----------------
// Bucket = dst >> 9 (512 nodes/bucket).  Chunk = 4096 edges/block.

__global__ __launch_bounds__(256) void k_bhist(const int* __restrict__ ei,
                                               int* __restrict__ gcnt,
                                               int E, int nblk, int nbkt) {
    __shared__ int cnt[256];
    const int t = threadIdx.x;
    cnt[t] = 0;
    __syncthreads();
    const int base = blockIdx.x * 4096;
#pragma unroll
    for (int i = 0; i < 16; ++i) {
        const int e = base + i * 256 + t;
        if (e < E) atomicAdd(&cnt[ei[E + e] >> 9], 1);
    }
    __syncthreads();
    if (t < nbkt) gcnt[t * nblk + blockIdx.x] = cnt[t];
}

// Hierarchical exclusive scan over g[0..L): block-local in place + bsum.
__global__ __launch_bounds__(256) void k_scan_block2(int* __restrict__ g,
                                                     int* __restrict__ bsum, int L) {
    __shared__ int s[256];
    const int t = threadIdx.x;
    const int i = blockIdx.x * 256 + t;
    const int v = (i < L) ? g[i] : 0;
    s[t] = v;
    __syncthreads();
    for (int off = 1; off < 256; off <<= 1) {
        const int tv = (t >= off) ? s[t - off] : 0;
        __syncthreads();
        s[t] += tv;
        __syncthreads();
    }
    if (i < L) g[i] = s[t] - v;
    if (t == 255) bsum[blockIdx.x] = s[255];
}

__global__ __launch_bounds__(1024) void k_scan_sums(int* __restrict__ bsum, int NB) {
    __shared__ int s[1024];
    const int t = threadIdx.x;
    const int v = (t < NB) ? bsum[t] : 0;
    s[t] = v;
    __syncthreads();
    for (int off = 1; off < 1024; off <<= 1) {
        const int tv = (t >= off) ? s[t - off] : 0;
        __syncthreads();
        s[t] += tv;
        __syncthreads();
    }
    if (t < NB) bsum[t] = s[t] - v;
}

__global__ __launch_bounds__(256) void k_scan_add2(int* __restrict__ g,
                                                   const int* __restrict__ bsum, int L) {
    const int i = blockIdx.x * 256 + threadIdx.x;
    if (i < L) g[i] += bsum[blockIdx.x];
}

// Scatter (src,dst) records into per-(bucket,block) contiguous runs.
__global__ __launch_bounds__(256) void k_bucket_scatter(const int* __restrict__ ei,
                                                        const int* __restrict__ gbase,
                                                        int2* __restrict__ buf2,
                                                        int E, int nblk, int nbkt) {
    __shared__ int cnt[256];
    __shared__ int sbase[256];
    const int t = threadIdx.x;
    cnt[t] = 0;
    if (t < nbkt) sbase[t] = gbase[t * nblk + blockIdx.x];
    __syncthreads();
    const int base = blockIdx.x * 4096;
#pragma unroll
    for (int i = 0; i < 16; ++i) {
        const int e = base + i * 256 + t;
        if (e < E) {
            const int src = ei[e];
            const int dst = ei[E + e];
            const int b = dst >> 9;
            const int r = atomicAdd(&cnt[b], 1);
            buf2[sbase[b] + r] = make_int2(src, dst);
        }
    }
}

// Per-bucket fine CSR: LDS hist(512) -> scan -> rowptr + esrc/sdst (dense).
__global__ __launch_bounds__(256) void k_bucket_csr(const int2* __restrict__ buf2,
                                                    const int* __restrict__ gbase,
                                                    int* __restrict__ rowptr,
                                                    int* __restrict__ esrc,
                                                    int* __restrict__ sdst,
                                                    int N, int E, int nblk, int nbkt) {
    __shared__ int hist[512], curs[512], ps[256];
    __shared__ int sh_base, sh_end;
    const int t = threadIdx.x;
    const int b = blockIdx.x;
    const int node0 = b << 9;
    if (t == 0) {
        sh_base = gbase[b * nblk];
        sh_end  = (b + 1 < nbkt) ? gbase[(b + 1) * nblk] : E;
        if (b == 0) rowptr[N] = E;
    }
    hist[t] = 0;
    hist[t + 256] = 0;
    __syncthreads();
    const int eb = sh_base, ee = sh_end;
    for (int e = eb + t; e < ee; e += 256)
        atomicAdd(&hist[buf2[e].y - node0], 1);
    __syncthreads();
    const int p0 = hist[2 * t], p1 = hist[2 * t + 1];
    const int pr = p0 + p1;
    ps[t] = pr;
    __syncthreads();
    for (int off = 1; off < 256; off <<= 1) {
        const int v = (t >= off) ? ps[t - off] : 0;
        __syncthreads();
        ps[t] += v;
        __syncthreads();
    }
    const int e0 = ps[t] - pr;
    curs[2 * t]     = e0;
    curs[2 * t + 1] = e0 + p0;
    const int nn = min(512, N - node0);
    if (2 * t < nn)     rowptr[node0 + 2 * t]     = eb + e0;
    if (2 * t + 1 < nn) rowptr[node0 + 2 * t + 1] = eb + e0 + p0;
    __syncthreads();
    for (int e = eb + t; e < ee; e += 256) {
        const int2 r = buf2[e];
        const int rk = atomicAdd(&curs[r.y - node0], 1);
        esrc[eb + rk] = r.x;
        sdst[eb + rk] = r.y;
    }
}

// ---------------- legacy CSR build (fallback path only) ----------------
__global__ __launch_bounds__(256) void k_hist(const int* __restrict__ ei,
                                              int* __restrict__ deg, int E) {
    const int e = blockIdx.x * 256 + threadIdx.x;
    if (e < E) atomicAdd(&deg[ei[E + e]], 1);
}

__global__ __launch_bounds__(256) void k_scan_block(const int* __restrict__ deg,
                                                    int* __restrict__ rowptr,
                                                    int* __restrict__ bsum, int N) {
    __shared__ int s[256];
    const int t = threadIdx.x;
    const int i = blockIdx.x * 256 + t;
    const int v = (i < N) ? deg[i] : 0;
    s[t] = v;
    __syncthreads();
    for (int off = 1; off < 256; off <<= 1) {
        const int tv = (t >= off) ? s[t - off] : 0;
        __syncthreads();
        s[t] += tv;
        __syncthreads();
    }
    if (i < N) rowptr[i] = s[t] - v;
    if (t == 255) bsum[blockIdx.x] = s[255];
}

__global__ __launch_bounds__(256) void k_scan_add(int* __restrict__ rowptr,
                                                  const int* __restrict__ bsum,
                                                  int* __restrict__ cursor, int N, int E) {
    const int i = blockIdx.x * 256 + threadIdx.x;
    if (i < N) {
        const int r = rowptr[i] + bsum[blockIdx.x];
        rowptr[i] = r;
        cursor[i] = r;
    }
    if (i == 0) rowptr[N] = E;
}

__global__ __launch_bounds__(256) void k_scatter(const int* __restrict__ ei,
                                                 int* __restrict__ cursor,
                                                 int* __restrict__ esrc, int E) {
    const int e = blockIdx.x * 256 + threadIdx.x;
    if (e >= E) return;
    const int src = ei[e];
    const int dst = ei[E + e];
    const int pos = atomicAdd(&cursor[dst], 1);
    esrc[pos] = src;
}

// ---------------- main-path GEMM: 4x8 register tile, W in LDS (KC=16) -------
template <int IN, int C, int F>
__global__ __launch_bounds__(256) void k_gemm_big(const float* __restrict__ x,
                                                  const float* __restrict__ W,
                                                  __half* __restrict__ h, int N) {
    constexpr int CJ = C / 32;
    constexpr int KC = 16;
    __shared__ float xs[32 * IN];
    __shared__ float wlds[KC * (C + 4)];
    const int t  = threadIdx.x;
    const int n0 = blockIdx.x * 32;

    const float4* src4 = (const float4*)(x + (size_t)n0 * IN);
    float4* xs4 = (float4*)xs;
    constexpr int NV = 32 * IN / 4;
    for (int idx = t; idx < NV; idx += 256) {
        const int row = idx / (IN / 4);
        xs4[idx] = (n0 + row < N) ? src4[idx] : make_float4(0.f, 0.f, 0.f, 0.f);
    }

    const int tc = t & 31;
    const int tr = t >> 5;
    float acc[4][CJ];
#pragma unroll
    for (int i = 0; i < 4; ++i)
#pragma unroll
        for (int j = 0; j < CJ; ++j) acc[i][j] = 0.f;

#pragma unroll 1
    for (int kc = 0; kc < IN; kc += KC) {
        __syncthreads();
        for (int idx = t; idx < KC * C; idx += 256) {
            const int k = idx / C, c = idx % C;
            wlds[k * (C + 4) + c] = W[(size_t)(kc + k) * C + c];
        }
        __syncthreads();
#pragma unroll 1
        for (int q = 0; q < KC / 4; ++q) {
            float4 xv[4];
#pragma unroll
            for (int i = 0; i < 4; ++i)
                xv[i] = *(const float4*)&xs[(tr * 4 + i) * IN + kc + q * 4];
#pragma unroll
            for (int kk = 0; kk < 4; ++kk) {
                float wv[CJ];
#pragma unroll
                for (int j = 0; j < CJ; ++j)
                    wv[j] = wlds[(q * 4 + kk) * (C + 4) + tc + j * 32];
#pragma unroll
                for (int i = 0; i < 4; ++i) {
                    const float xvv = ((const float*)&xv[i])[kk];
#pragma unroll
                    for (int j = 0; j < CJ; ++j)
                        acc[i][j] = fmaf(xvv, wv[j], acc[i][j]);
                }
            }
        }
    }

    if constexpr (C == 256 && F == 32) {
#pragma unroll
        for (int i = 0; i < 4; ++i) {
            const int r = n0 + tr * 4 + i;
            if (r < N) {
                __half tmp[8];
#pragma unroll
                for (int j = 0; j < 8; ++j) tmp[j] = __float2half(acc[i][j]);
                *(float4*)(h + (size_t)r * 256 + tc * 8) = *(const float4*)tmp;
            }
        }
    } else {
#pragma unroll
        for (int i = 0; i < 4; ++i) {
            const int r = n0 + tr * 4 + i;
            if (r < N) {
#pragma unroll
                for (int j = 0; j < CJ; ++j) {
                    const int c = tc + j * 32;
                    h[(size_t)r * C + (c % F) * 8 + (c / F)] = __float2half(acc[i][j]);
                }
            }
        }
    }
}

// Attention dots from fp16 h [N, F, HG]; writes a_s/a_d [N,8] at head hb+hl.
template <int F, int HG>
__global__ __launch_bounds__(256) void k_dots_h(const __half* __restrict__ h,
                                                const float* __restrict__ atts,
                                                const float* __restrict__ attd,
                                                float* __restrict__ as_,
                                                float* __restrict__ ad_, int N, int hb) {
    const int i = blockIdx.x * 256 + threadIdx.x;
    if (i >= N * HG) return;
    const int n  = i / HG;
    const int hl = i % HG;
    const int hg = hb + hl;
    const __half* hp = h + (size_t)n * (F * HG) + hl;
    const float* sv = atts + hg * F;
    const float* dv = attd + hg * F;
    float s = 0.f, d = 0.f;
#pragma unroll
    for (int f = 0; f < F; ++f) {
        const float v = __half2float(hp[f * HG]);
        s = fmaf(v, sv[f], s);
        d = fmaf(v, dv[f], d);
    }
    as_[(size_t)n * 8 + hg] = s;
    ad_[(size_t)n * 8 + hg] = d;
}

// Slot-parallel alpha: coalesced esrc/sdst reads, L2 gathers, coalesced store.
__global__ __launch_bounds__(256) void k_alpha_csr(const int* __restrict__ esrc,
                                                   const int* __restrict__ sdst,
                                                   const float* __restrict__ as_,
                                                   const float* __restrict__ ad_,
                                                   __half* __restrict__ exbuf, int E) {
    const int p = blockIdx.x * 256 + threadIdx.x;
    if (p >= E) return;
    const int src = esrc[p];
    const int dst = sdst[p];
    const float4 s0 = *(const float4*)(as_ + (size_t)src * 8);
    const float4 s1 = *(const float4*)(as_ + (size_t)src * 8 + 4);
    const float4 d0 = *(const float4*)(ad_ + (size_t)dst * 8);
    const float4 d1 = *(const float4*)(ad_ + (size_t)dst * 8 + 4);
    __half tmp[8];
    tmp[0] = __float2half(lrelu_exp(s0.x + d0.x));
    tmp[1] = __float2half(lrelu_exp(s0.y + d0.y));
    tmp[2] = __float2half(lrelu_exp(s0.z + d0.z));
    tmp[3] = __float2half(lrelu_exp(s0.w + d0.w));
    tmp[4] = __float2half(lrelu_exp(s1.x + d1.x));
    tmp[5] = __float2half(lrelu_exp(s1.y + d1.y));
    tmp[6] = __float2half(lrelu_exp(s1.z + d1.z));
    tmp[7] = __float2half(lrelu_exp(s1.w + d1.w));
    *(float4*)(exbuf + (size_t)p * 8) = *(const float4*)tmp;
}

// Single-pass aggregation; denominator fused into the edge loop.
template <int F, int MODE>
__global__ __launch_bounds__(256) void k_agg_ex2(const int* __restrict__ rowptr,
                                                 const int* __restrict__ esrc,
                                                 const __half* __restrict__ exbuf,
                                                 const __half* __restrict__ h,
                                                 const float* __restrict__ bias,
                                                 float* __restrict__ outp, int N) {
    constexpr int NPB = 256 / F;
    const int n = blockIdx.x * NPB + threadIdx.x / F;
    const int f = threadIdx.x % F;
    if (n >= N) return;
    const int r0 = rowptr[n], r1 = rowptr[n + 1];

    float acc[8], den[8];
#pragma unroll
    for (int k = 0; k < 8; ++k) { acc[k] = 0.f; den[k] = 0.f; }

    for (int e = r0; e < r1; ++e) {
        const int src = esrc[e];
        const float4 exr = *(const float4*)(exbuf + (size_t)e * 8);
        const float4 raw = *(const float4*)(h + (size_t)src * (F * 8) + f * 8);
        const __half2* e2 = (const __half2*)&exr;
        const __half2* h2 = (const __half2*)&raw;
#pragma unroll
        for (int k = 0; k < 4; ++k) {
            const float2 ef = __half22float2(e2[k]);
            const float2 hf = __half22float2(h2[k]);
            acc[2 * k]     = fmaf(ef.x, hf.x, acc[2 * k]);
            acc[2 * k + 1] = fmaf(ef.y, hf.y, acc[2 * k + 1]);
            den[2 * k]     += ef.x;
            den[2 * k + 1] += ef.y;
        }
    }
    float s = 0.f;
#pragma unroll
    for (int k = 0; k < 8; ++k) s += acc[k] / (den[k] + 1e-16f);
    float v = 0.125f * s + bias[f];
    if constexpr (MODE == 1) v = v > 0.f ? v : 0.f;
    outp[(size_t)n * F + f] = v;
}

// ---------------- fallback path (r8-proven) ----------------
template <int IN, int C, int OW, int F>
__global__ __launch_bounds__(256) void k_gemm_h(const float* __restrict__ x,
                                                const float* __restrict__ W,
                                                __half* __restrict__ h, int N, int c0) {
    constexpr int HG = C / F;
    __shared__ float xs[32 * IN];
    const int t  = threadIdx.x;
    const int n0 = blockIdx.x * 32;
    const float4* src4 = (const float4*)(x + (size_t)n0 * IN);
    float4* xs4 = (float4*)xs;
    constexpr int NV = 32 * IN / 4;
    for (int idx = t; idx < NV; idx += 256) {
        const int row = idx / (IN / 4);
        xs4[idx] = (n0 + row < N) ? src4[idx] : make_float4(0.f, 0.f, 0.f, 0.f);
    }
    __syncthreads();
    const int idx = t % C;
    const int r0  = t / C;
    constexpr int RSTEP = 256 / C;
    constexpr int RPT   = 32 / RSTEP;
    const int f  = idx / HG;
    const int hd = idx % HG;
    float acc[RPT];
#pragma unroll
    for (int i = 0; i < RPT; ++i) acc[i] = 0.f;
    const float* Wc = W + c0 + hd * F + f;
#pragma unroll 1
    for (int k = 0; k < IN; k += 4) {
        const float w0 = Wc[(k + 0) * OW];
        const float w1 = Wc[(k + 1) * OW];
        const float w2 = Wc[(k + 2) * OW];
        const float w3 = Wc[(k + 3) * OW];
#pragma unroll
        for (int i = 0; i < RPT; ++i) {
            const int r = r0 + i * RSTEP;
            const float4 xv = *(const float4*)&xs[r * IN + k];
            acc[i] = fmaf(xv.x, w0, fmaf(xv.y, w1, fmaf(xv.z, w2, fmaf(xv.w, w3, acc[i]))));
        }
    }
#pragma unroll
    for (int i = 0; i < RPT; ++i) {
        const int r = r0 + i * RSTEP;
        if (n0 + r < N) h[(size_t)(n0 + r) * C + idx] = __float2half(acc[i]);
    }
}

template <int HG>
__global__ __launch_bounds__(256) void k_denom(const int* __restrict__ rowptr,
                                               const int* __restrict__ esrc,
                                               const float* __restrict__ as_,
                                               const float* __restrict__ ad_,
                                               float* __restrict__ rinv, int N, int hb) {
    const int i = blockIdx.x * 256 + threadIdx.x;
    if (i >= N * HG) return;
    const int n  = i / HG;
    const int hl = i % HG;
    const float ad = ad_[(size_t)n * 8 + hb + hl];
    const int r0 = rowptr[n];
    const int r1 = rowptr[n + 1];
    float s = 0.f;
    for (int e = r0; e < r1; ++e)
        s += lrelu_exp(as_[(size_t)esrc[e] * 8 + hb + hl] + ad);
    rinv[(size_t)n * 8 + hb + hl] = 1.f / (s + 1e-16f);
}

template <int F, int HG>
__global__ __launch_bounds__(256) void k_csr_agg_hg(const int* __restrict__ rowptr,
                                                    const int* __restrict__ esrc,
                                                    const float* __restrict__ as_,
                                                    const float* __restrict__ ad_,
                                                    const float* __restrict__ rinv,
                                                    const __half* __restrict__ h,
                                                    float* __restrict__ outp,
                                                    int N, int hb) {
    constexpr int NPB = 256 / F;
    const int n = blockIdx.x * NPB + threadIdx.x / F;
    const int f = threadIdx.x % F;
    if (n >= N) return;
    const int r0 = rowptr[n];
    const int r1 = rowptr[n + 1];
    float ad[HG], rv[HG];
#pragma unroll
    for (int k = 0; k < HG; ++k) {
        ad[k] = ad_[(size_t)n * 8 + hb + k];
        rv[k] = rinv[(size_t)n * 8 + hb + k];
    }
    float a0 = 0.f;
    for (int e = r0; e < r1; ++e) {
        const int src = esrc[e];
        const float* sp = as_ + (size_t)src * 8 + hb;
        const __half* hp = h + (size_t)src * (F * HG) + f * HG;
#pragma unroll
        for (int k = 0; k < HG; ++k) {
            const float al = lrelu_exp(sp[k] + ad[k]) * rv[k];
            a0 = fmaf(al, __half2float(hp[k]), a0);
        }
    }
    outp[(size_t)n * F + f] += 0.125f * a0;
}

__global__ __launch_bounds__(256) void k_relu_bias(float* __restrict__ a,
                                                   const float* __restrict__ b, int total) {
    const int i = blockIdx.x * 256 + threadIdx.x;
    if (i < total) {
        const float v = a[i] + b[i & 31];
        a[i] = v > 0.f ? v : 0.f;
    }
}

__global__ __launch_bounds__(256) void k_bias_inplace(float* __restrict__ a,
                                                      const float* __restrict__ b, int total) {
    const int i = blockIdx.x * 256 + threadIdx.x;
    if (i < total) a[i] += b[i & 15];
}

// ---------------- drivers ----------------
static void run_full(const float* x, const int* ei,
                     const float* W1, const float* as1, const float* ad1, const float* b1,
                     const float* W2, const float* as2, const float* ad2, const float* b2,
                     float* out, int N, int E, char* ws, hipStream_t stream) {
    auto align256 = [](size_t b) { return (b + 255) & ~(size_t)255; };
    size_t off = 0;
    auto alloc = [&](size_t bytes) { char* p = ws + off; off += align256(bytes); return p; };

    const int NBLKC = (E + 4095) / 4096;
    const int nbkt  = (N + 511) >> 9;
    const int L     = nbkt * NBLKC;

    __half* hbuf  = (__half*)alloc((size_t)N * 256 * 2);
    __half* exbuf = (__half*)alloc((size_t)E * 8 * 2);
    float* a_s    = (float*)alloc((size_t)N * 8 * 4);
    float* a_d    = (float*)alloc((size_t)N * 8 * 4);
    size_t acc_bytes = (size_t)N * 32 * 4;
    size_t buf2_bytes = (size_t)E * 8;
    float* acc1   = (float*)alloc(acc_bytes > buf2_bytes ? acc_bytes : buf2_bytes);
    int2* buf2    = (int2*)acc1;            // aliased: buf2 dead before agg1 writes acc1
    int* rowptr   = (int*)alloc((size_t)(N + 1) * 4);
    int* esrc     = (int*)alloc((size_t)E * 4);
    int* sdst     = (int*)alloc((size_t)E * 4);
    int* gcnt     = (int*)alloc((size_t)L * 4);
    int* bsum2    = (int*)alloc(1024 * 4);

    // ---- bucket-sort CSR build (no global atomics, parallel scan) ----
    const int NBs = (L + 255) / 256;  // <= 1024 for N<=131072, E<=16.7M
    k_bhist<<<NBLKC, 256, 0, stream>>>(ei, gcnt, E, NBLKC, nbkt);
    k_scan_block2<<<NBs, 256, 0, stream>>>(gcnt, bsum2, L);
    k_scan_sums<<<1, 1024, 0, stream>>>(bsum2, NBs);
    k_scan_add2<<<NBs, 256, 0, stream>>>(gcnt, bsum2, L);
    k_bucket_scatter<<<NBLKC, 256, 0, stream>>>(ei, gcnt, buf2, E, NBLKC, nbkt);
    k_bucket_csr<<<nbkt, 256, 0, stream>>>(buf2, gcnt, rowptr, esrc, sdst, N, E, NBLKC, nbkt);

    const int NBg = (N + 31) / 32;
    const int nbp = (N * 8 + 255) / 256;
    const int NBe = (E + 255) / 256;
    // layer 1
    k_gemm_big<128, 256, 32><<<NBg, 256, 0, stream>>>(x, W1, hbuf, N);
    k_dots_h<32, 8><<<nbp, 256, 0, stream>>>(hbuf, as1, ad1, a_s, a_d, N, 0);
    k_alpha_csr<<<NBe, 256, 0, stream>>>(esrc, sdst, a_s, a_d, exbuf, E);
    k_agg_ex2<32, 1><<<(N + 7) / 8, 256, 0, stream>>>(rowptr, esrc, exbuf, hbuf, b1, acc1, N);
    // layer 2
    k_gemm_big<32, 128, 16><<<NBg, 256, 0, stream>>>(acc1, W2, hbuf, N);
    k_dots_h<16, 8><<<nbp, 256, 0, stream>>>(hbuf, as2, ad2, a_s, a_d, N, 0);
    k_alpha_csr<<<NBe, 256, 0, stream>>>(esrc, sdst, a_s, a_d, exbuf, E);
    k_agg_ex2<16, 2><<<(N + 15) / 16, 256, 0, stream>>>(rowptr, esrc, exbuf, hbuf, b2, out, N);
}

static void run_fallback4(const float* x, const int* ei,
                          const float* W1, const float* as1, const float* ad1, const float* b1,
                          const float* W2, const float* as2, const float* ad2, const float* b2,
                          float* out, int N, int E, char* ws, hipStream_t stream) {
    constexpr int HG = 4;
    auto align256 = [](size_t b) { return (b + 255) & ~(size_t)255; };
    size_t off = 0;
    auto alloc = [&](size_t bytes) { char* p = ws + off; off += align256(bytes); return p; };

    __half* hbuf = (__half*)alloc((size_t)N * HG * 32 * 2);
    float* a_s   = (float*)alloc((size_t)N * 8 * 4);
    float* a_d   = (float*)alloc((size_t)N * 8 * 4);
    float* rinv  = (float*)alloc((size_t)N * 8 * 4);
    float* acc1  = (float*)alloc((size_t)N * 32 * 4);
    int* rowptr  = (int*)alloc((size_t)(N + 1) * 4);
    int* cursor  = (int*)alloc((size_t)N * 4);
    int* deg     = (int*)alloc((size_t)N * 4);
    int* bsum    = (int*)alloc(1024 * 4);
    int* esrc    = (int*)alloc((size_t)E * 4);

    const int NBn = (N + 255) / 256;
    const int NBe = (E + 255) / 256;
    k_zero_int<<<512, 256, 0, stream>>>(deg, N);
    k_hist<<<NBe, 256, 0, stream>>>(ei, deg, E);
    k_scan_block<<<NBn, 256, 0, stream>>>(deg, rowptr, bsum, N);
    k_scan_sums<<<1, 1024, 0, stream>>>(bsum, NBn);
    k_scan_add<<<NBn, 256, 0, stream>>>(rowptr, bsum, cursor, N, E);
    k_scatter<<<NBe, 256, 0, stream>>>(ei, cursor, esrc, E);

    k_zero<<<512, 256, 0, stream>>>(acc1, N * 32);
    k_zero<<<512, 256, 0, stream>>>(out, N * 16);

    const int nbp = (N * HG + 255) / 256;
    for (int g = 0; g < 2; ++g) {
        k_gemm_h<128, 128, 256, 32><<<NBn * 8, 256, 0, stream>>>(x, W1, hbuf, N, g * 128);
        k_dots_h<32, HG><<<nbp, 256, 0, stream>>>(hbuf, as1, ad1, a_s, a_d, N, g * HG);
        k_denom<HG><<<nbp, 256, 0, stream>>>(rowptr, esrc, a_s, a_d, rinv, N, g * HG);
        k_csr_agg_hg<32, HG><<<(N + 7) / 8, 256, 0, stream>>>(rowptr, esrc, a_s, a_d, rinv,
                                                              hbuf, acc1, N, g * HG);
    }
    k_relu_bias<<<(N * 32 + 255) / 256, 256, 0, stream>>>(acc1, b1, N * 32);

    for (int g = 0; g < 2; ++g) {
        k_gemm_h<32, 64, 128, 16><<<NBn * 8, 256, 0, stream>>>(acc1, W2, hbuf, N, g * 64);
        k_dots_h<16, HG><<<nbp, 256, 0, stream>>>(hbuf, as2, ad2, a_s, a_d, N, g * HG);
        k_denom<HG><<<nbp, 256, 0, stream>>>(rowptr, esrc, a_s, a_d, rinv, N, g * HG);
        k_csr_agg_hg<16, HG><<<(N + 15) / 16, 256, 0, stream>>>(rowptr, esrc, a_s, a_d, rinv,
                                                                hbuf, out, N, g * HG);
    }
    k_bias_inplace<<<(N * 16 + 255) / 256, 256, 0, stream>>>(out, b2, N * 16);
}

extern "C" void kernel_launch(void* const* d_in, const int* in_sizes, int n_in,
                              void* d_out, int out_size, void* d_ws, size_t ws_size,
                              hipStream_t stream) {
    const float* x   = (const float*)d_in[0];
    const int*   ei  = (const int*)d_in[1];
    const float* W1  = (const float*)d_in[2];
    const float* as1 = (const float*)d_in[3];
    const float* ad1 = (const float*)d_in[4];
    const float* b1  = (const float*)d_in[5];
    const float* W2  = (const float*)d_in[6];
    const float* as2 = (const float*)d_in[7];
    const float* ad2 = (const float*)d_in[8];
    const float* b2  = (const float*)d_in[9];
    float* out = (float*)d_out;

    const int N = in_sizes[0] / 128;
    const int E = in_sizes[1] / 2;

    const int NBLKC = (E + 4095) / 4096;
    const int nbkt  = (N + 511) >> 9;
    const int L     = nbkt * NBLKC;
    const size_t acc_or_buf2 = ((size_t)N * 32 * 4 > (size_t)E * 8) ? (size_t)N * 32 * 4
                                                                    : (size_t)E * 8;
    const size_t need_full = (size_t)2 * N * 256 + (size_t)2 * E * 8 +
                             (size_t)4 * N * 16 + acc_or_buf2 +
                             (size_t)4 * (N + 1) + (size_t)8 * E +
                             (size_t)4 * L + 4096 + 20 * 256;
    char* ws = (char*)d_ws;
    if (ws_size >= need_full && nbkt <= 256 && (L + 255) / 256 <= 1024) {
        run_full(x, ei, W1, as1, ad1, b1, W2, as2, ad2, b2, out, N, E, ws, stream);
    } else {
        run_fallback4(x, ei, W1, as1, ad1, b1, W2, as2, ad2, b2, out, N, E, ws, stream);
    }
}